// Round 2
// 121.682 us; speedup vs baseline: 1.0048x; 1.0048x over previous
//
#include <hip/hip_runtime.h>

// B = 4194304 rows, x is (B,4) fp32 row-major. Three 3->4->1 MLPs; output
// selected by sel = x[:,1] in {0,1,2}. Memory-bound: 83.9 MB traffic,
// ~13.3 us floor at 6.3 TB/s achievable.
//
// Revision notes (same as prior round; re-submitted after infra failure):
//  - ROWS=4 per thread, all 4 float4 row-loads issued before any compute
//    (independent -> 4x in-flight bytes per wave, better latency tolerance).
//    Per instruction: lane-contiguous float4 (16 B/lane, 4 KiB/wave) = perfect
//    coalescing. Rows for thread t in block b: b*1024 + t + k*256, k=0..3.
//  - sigmoid via native v_exp_f32 (exp2 formulation) + v_rcp_f32 instead of
//    full-precision divide sequence (~10 instr -> 1; tol is 1e-2, rcp is 1ulp).
//  - non-temporal stores: out is write-once, keep x resident in L2/L3.

#define ROWS 4

__global__ __launch_bounds__(256) void Program_72902774882571_kernel(
    const float* __restrict__ x,
    const float* __restrict__ Ws1, const float* __restrict__ bs1,
    const float* __restrict__ Ws2, const float* __restrict__ bs2,
    const float* __restrict__ Wu1, const float* __restrict__ bu1,
    const float* __restrict__ Wu2, const float* __restrict__ bu2,
    const float* __restrict__ Wd1, const float* __restrict__ bd1,
    const float* __restrict__ Wd2, const float* __restrict__ bd2,
    float* __restrict__ out, int n)
{
    const int base = blockIdx.x * (256 * ROWS) + threadIdx.x;

    // Issue all row loads first; they are independent.
    float4 xv[ROWS];
#pragma unroll
    for (int k = 0; k < ROWS; ++k) {
        const int i = base + k * 256;
        xv[k] = make_float4(0.f, -1.f, 0.f, 0.f);  // sel=-1 -> result 0
        if (i < n) xv[k] = reinterpret_cast<const float4*>(x)[i];
    }

    // Tiny MLP: h = relu(x3 @ W1 + b1) ; out = sigmoid(h @ W2 + b2)
    // W1 is (3,4) row-major, W2 is (4,1). Weight loads are wave-uniform
    // addresses -> scalarized + CSE'd across the 12 call sites by the compiler.
    auto net = [&](float x0, float x1, float x2,
                   const float* __restrict__ W1, const float* __restrict__ b1,
                   const float* __restrict__ W2, const float* __restrict__ b2) -> float {
        float acc = b2[0];
#pragma unroll
        for (int j = 0; j < 4; ++j) {
            float h = b1[j];
            h = fmaf(x0, W1[0 * 4 + j], h);
            h = fmaf(x1, W1[1 * 4 + j], h);
            h = fmaf(x2, W1[2 * 4 + j], h);
            h = fmaxf(h, 0.0f);          // relu
            acc = fmaf(h, W2[j], acc);
        }
        // sigmoid(a) = rcp(1 + exp2(-a*log2(e))) ; native trans ops, ~1ulp
        const float e = __builtin_amdgcn_exp2f(acc * -1.44269504088896340736f);
        return __builtin_amdgcn_rcpf(1.0f + e);
    };

#pragma unroll
    for (int k = 0; k < ROWS; ++k) {
        const int i = base + k * 256;
        if (i >= n) continue;   // never taken at B=4194304 (exact multiple)
        const float x0 = xv[k].x, x1 = xv[k].y, x2 = xv[k].z;

        const float os = net(x0, x1, x2, Ws1, bs1, Ws2, bs2);
        const float ou = net(x0, x1, x2, Wu1, bu1, Wu2, bu2);
        const float od = net(x0, x1, x2, Wd1, bd1, Wd2, bd2);

        // where(sel==0, s, where(sel==1, u, where(sel==2, d, 0)))
        float r = (x1 == 2.0f) ? od : 0.0f;
        r = (x1 == 1.0f) ? ou : r;
        r = (x1 == 0.0f) ? os : r;

        __builtin_nontemporal_store(r, &out[i]);  // 4 B/lane, coalesced
    }
}

extern "C" void kernel_launch(void* const* d_in, const int* in_sizes, int n_in,
                              void* d_out, int out_size, void* d_ws, size_t ws_size,
                              hipStream_t stream) {
    const float* x   = (const float*)d_in[0];
    const float* Ws1 = (const float*)d_in[1];
    const float* bs1 = (const float*)d_in[2];
    const float* Ws2 = (const float*)d_in[3];
    const float* bs2 = (const float*)d_in[4];
    const float* Wu1 = (const float*)d_in[5];
    const float* bu1 = (const float*)d_in[6];
    const float* Wu2 = (const float*)d_in[7];
    const float* bu2 = (const float*)d_in[8];
    const float* Wd1 = (const float*)d_in[9];
    const float* bd1 = (const float*)d_in[10];
    const float* Wd2 = (const float*)d_in[11];
    const float* bd2 = (const float*)d_in[12];

    const int n = out_size;  // B = 4194304 rows
    const int block = 256;
    const int rows_per_block = block * ROWS;                 // 1024
    const int grid = (n + rows_per_block - 1) / rows_per_block;  // 4096 blocks

    Program_72902774882571_kernel<<<grid, block, 0, stream>>>(
        x, Ws1, bs1, Ws2, bs2, Wu1, bu1, Wu2, bu2, Wd1, bd1, Wd2, bd2,
        (float*)d_out, n);
}